// Round 1
// baseline (701.550 us; speedup 1.0000x reference)
//
#include <hip/hip_runtime.h>

#define NG   8192
#define NSH  4
#define HH   1024
#define WW   1024
#define PP   48
#define S_MIN (1.0f / 30.0f)
#define S_MAX (1.0f / 0.75f)
#define TWO_PI 6.28318530717958647692f

// d_ws layout:
//   [0, NG*48)            : per-gaussian params, 3 x float4 each
//       p0 = {mu_px, mu_py, S0*c, S0*s}
//       p1 = {-S1*s, S1*c, op, r}
//       p2 = {g, b, base_x(float), base_y(float)}
//   [NG*48, NG*48+4MB)    : w_acc plane (H*W floats)

__global__ void prep_kernel(const float* __restrict__ xyz,
                            const float* __restrict__ feat,
                            const float* __restrict__ opac,
                            const float* __restrict__ scal,
                            const float* __restrict__ rot,
                            float4* __restrict__ params) {
    int g = blockIdx.x * blockDim.x + threadIdx.x;
    if (g >= NG) return;

    float mx = fminf(fmaxf(xyz[2 * g + 0], -1.0f), 1.0f) * 1.05f;
    float my = fminf(fmaxf(xyz[2 * g + 1], -1.0f), 1.0f) * 1.05f;
    float s0 = fminf(fmaxf(scal[2 * g + 0], 0.0f), 1.0f) * (S_MAX - S_MIN) + S_MIN;
    float s1 = fminf(fmaxf(scal[2 * g + 1], 0.0f), 1.0f) * (S_MAX - S_MIN) + S_MIN;
    float rr = rot[g];
    float ang = (rr - floorf(rr)) * TWO_PI;
    float op = fminf(fmaxf(opac[g], 0.0f), 1.0f);

    float c = cosf(ang), s = sinf(ang);

    // circular harmonics: basis [1, sin t, cos t, sin 2t, cos 2t, ...]
    const float* f = feat + g * (2 * NSH + 1) * 3;
    float r = f[0], gg = f[1], b = f[2];
    #pragma unroll
    for (int i = 1; i <= NSH; ++i) {
        float si = sinf(ang * (float)i);
        float ci = cosf(ang * (float)i);
        int ms = (2 * i - 1) * 3, mc = (2 * i) * 3;
        r  += si * f[ms + 0] + ci * f[mc + 0];
        gg += si * f[ms + 1] + ci * f[mc + 1];
        b  += si * f[ms + 2] + ci * f[mc + 2];
    }

    float mu_px = (mx + 1.0f) * 0.5f * (float)(WW - 1);
    float mu_py = (my + 1.0f) * 0.5f * (float)(HH - 1);
    float bx = floorf(mu_px), by = floorf(mu_py);

    params[3 * g + 0] = make_float4(mu_px, mu_py, s0 * c, s0 * s);
    params[3 * g + 1] = make_float4(-s1 * s, s1 * c, op, r);
    params[3 * g + 2] = make_float4(gg, b, bx, by);
}

__global__ void splat_kernel(const float4* __restrict__ params,
                             float* __restrict__ out_rgb,
                             float* __restrict__ wacc) {
    int t = blockIdx.x * blockDim.x + threadIdx.x;   // < NG*PP*PP = 18.9M
    int g   = t / (PP * PP);
    int rem = t - g * (PP * PP);
    int oy = rem / PP;
    int ox = rem - oy * PP;

    float4 p0 = params[3 * g + 0];
    float4 p1 = params[3 * g + 1];
    float4 p2 = params[3 * g + 2];

    int px = (int)p2.z + ox - PP / 2;
    int py = (int)p2.w + oy - PP / 2;
    if (px < 0 || px >= WW || py < 0 || py >= HH) return;

    float dx = (float)px - p0.x;
    float dy = (float)py - p0.y;
    float vx = p0.z * dx + p0.w * dy;
    float vy = p1.x * dx + p1.y * dy;
    float w = p1.z * expf(-0.5f * (vx * vx + vy * vy));

    int idx = py * WW + px;
    atomicAdd(&out_rgb[3 * idx + 0], w * p1.w);
    atomicAdd(&out_rgb[3 * idx + 1], w * p2.x);
    atomicAdd(&out_rgb[3 * idx + 2], w * p2.y);
    atomicAdd(&wacc[idx], w);
}

__global__ void norm_kernel(float* __restrict__ out_rgb,
                            const float* __restrict__ wacc) {
    int i = blockIdx.x * blockDim.x + threadIdx.x;
    if (i >= HH * WW) return;
    float inv = 1.0f / (wacc[i] + 1e-6f);
    out_rgb[3 * i + 0] *= inv;
    out_rgb[3 * i + 1] *= inv;
    out_rgb[3 * i + 2] *= inv;
}

extern "C" void kernel_launch(void* const* d_in, const int* in_sizes, int n_in,
                              void* d_out, int out_size, void* d_ws, size_t ws_size,
                              hipStream_t stream) {
    const float* xyz  = (const float*)d_in[0];
    const float* feat = (const float*)d_in[1];
    const float* opac = (const float*)d_in[2];
    const float* scal = (const float*)d_in[3];
    const float* rot  = (const float*)d_in[4];
    float* out = (float*)d_out;

    char* ws = (char*)d_ws;
    float4* params = (float4*)ws;
    float* wacc = (float*)(ws + (size_t)NG * 48);

    hipMemsetAsync(out, 0, (size_t)HH * WW * 3 * sizeof(float), stream);
    hipMemsetAsync(wacc, 0, (size_t)HH * WW * sizeof(float), stream);

    prep_kernel<<<NG / 256, 256, 0, stream>>>(xyz, feat, opac, scal, rot, params);

    int total = NG * PP * PP;
    splat_kernel<<<total / 256, 256, 0, stream>>>(params, out, wacc);

    norm_kernel<<<(HH * WW) / 256, 256, 0, stream>>>(out, wacc);
}

// Round 2
// 127.067 us; speedup vs baseline: 5.5211x; 5.5211x over previous
//
#include <hip/hip_runtime.h>

#define NG   8192
#define NSH  4
#define HH   1024
#define WW   1024
#define PP   48            // footprint: x in [bx-24, bx+23]
#define TILE 16
#define TX   (WW / TILE)   // 64
#define TY   (HH / TILE)   // 64
#define NTILES (TX * TY)   // 4096
#define MAXLIST (NG * 16)  // each gaussian touches <= 4x4 tiles
#define CHUNK 128          // gaussians staged in LDS per render iteration
#define S_MIN (1.0f / 30.0f)
#define S_MAX (1.0f / 0.75f)
#define TWO_PI 6.28318530717958647692f

// d_ws layout (all 256B-aligned):
//   params : NG * 3 float4   (384 KB)
//     p0 = {mu_px, mu_py, S0*c, S0*s}
//     p1 = {-S1*s, S1*c, op, r}
//     p2 = {g, b, base_x(float), base_y(float)}
//   counts : NTILES int      (16 KB)   -- memset 0 each call
//   starts : NTILES+1 int
//   cursor : NTILES int
//   list   : MAXLIST int     (512 KB)

__global__ void prep_kernel(const float* __restrict__ xyz,
                            const float* __restrict__ feat,
                            const float* __restrict__ opac,
                            const float* __restrict__ scal,
                            const float* __restrict__ rot,
                            float4* __restrict__ params) {
    int g = blockIdx.x * blockDim.x + threadIdx.x;
    if (g >= NG) return;

    float mx = fminf(fmaxf(xyz[2 * g + 0], -1.0f), 1.0f) * 1.05f;
    float my = fminf(fmaxf(xyz[2 * g + 1], -1.0f), 1.0f) * 1.05f;
    float s0 = fminf(fmaxf(scal[2 * g + 0], 0.0f), 1.0f) * (S_MAX - S_MIN) + S_MIN;
    float s1 = fminf(fmaxf(scal[2 * g + 1], 0.0f), 1.0f) * (S_MAX - S_MIN) + S_MIN;
    float rr = rot[g];
    float ang = (rr - floorf(rr)) * TWO_PI;
    float op = fminf(fmaxf(opac[g], 0.0f), 1.0f);

    float c = cosf(ang), s = sinf(ang);

    const float* f = feat + g * (2 * NSH + 1) * 3;
    float r = f[0], gg = f[1], b = f[2];
    #pragma unroll
    for (int i = 1; i <= NSH; ++i) {
        float si = sinf(ang * (float)i);
        float ci = cosf(ang * (float)i);
        int ms = (2 * i - 1) * 3, mc = (2 * i) * 3;
        r  += si * f[ms + 0] + ci * f[mc + 0];
        gg += si * f[ms + 1] + ci * f[mc + 1];
        b  += si * f[ms + 2] + ci * f[mc + 2];
    }

    float mu_px = (mx + 1.0f) * 0.5f * (float)(WW - 1);
    float mu_py = (my + 1.0f) * 0.5f * (float)(HH - 1);
    float bx = floorf(mu_px), by = floorf(mu_py);

    params[3 * g + 0] = make_float4(mu_px, mu_py, s0 * c, s0 * s);
    params[3 * g + 1] = make_float4(-s1 * s, s1 * c, op, r);
    params[3 * g + 2] = make_float4(gg, b, bx, by);
}

// Clipped tile range of gaussian g. Returns false if fully off-screen.
__device__ __forceinline__ bool tile_range(const float4* params, int g,
                                           int& tx0, int& tx1, int& ty0, int& ty1) {
    float4 p2 = params[3 * g + 2];
    int bx = (int)p2.z, by = (int)p2.w;
    int x0 = bx - PP / 2, x1 = bx + PP / 2 - 1;
    int y0 = by - PP / 2, y1 = by + PP / 2 - 1;
    if (x1 < 0 || x0 > WW - 1 || y1 < 0 || y0 > HH - 1) return false;
    tx0 = max(x0, 0) / TILE;  tx1 = min(x1, WW - 1) / TILE;
    ty0 = max(y0, 0) / TILE;  ty1 = min(y1, HH - 1) / TILE;
    return true;
}

__global__ void count_kernel(const float4* __restrict__ params,
                             int* __restrict__ counts) {
    int g = blockIdx.x * blockDim.x + threadIdx.x;
    if (g >= NG) return;
    int tx0, tx1, ty0, ty1;
    if (!tile_range(params, g, tx0, tx1, ty0, ty1)) return;
    for (int ty = ty0; ty <= ty1; ++ty)
        for (int tx = tx0; tx <= tx1; ++tx)
            atomicAdd(&counts[ty * TX + tx], 1);
}

// single-block exclusive scan over NTILES counts -> starts[0..NTILES], cursor copy
__global__ void scan_kernel(const int* __restrict__ counts,
                            int* __restrict__ starts,
                            int* __restrict__ cursor) {
    __shared__ int sh[256];
    int t = threadIdx.x;
    const int E = NTILES / 256;   // 16
    int vals[E];
    int base = t * E, run = 0;
    #pragma unroll
    for (int i = 0; i < E; ++i) { vals[i] = counts[base + i]; run += vals[i]; }
    sh[t] = run;
    __syncthreads();
    for (int off = 1; off < 256; off <<= 1) {
        int v = (t >= off) ? sh[t - off] : 0;
        __syncthreads();
        sh[t] += v;
        __syncthreads();
    }
    int acc = (t == 0) ? 0 : sh[t - 1];
    #pragma unroll
    for (int i = 0; i < E; ++i) {
        starts[base + i] = acc;
        cursor[base + i] = acc;
        acc += vals[i];
    }
    if (t == 255) starts[NTILES] = acc;
}

__global__ void fill_kernel(const float4* __restrict__ params,
                            int* __restrict__ cursor,
                            int* __restrict__ list) {
    int g = blockIdx.x * blockDim.x + threadIdx.x;
    if (g >= NG) return;
    int tx0, tx1, ty0, ty1;
    if (!tile_range(params, g, tx0, tx1, ty0, ty1)) return;
    for (int ty = ty0; ty <= ty1; ++ty)
        for (int tx = tx0; tx <= tx1; ++tx) {
            int pos = atomicAdd(&cursor[ty * TX + tx], 1);
            list[pos] = g;
        }
}

__global__ void __launch_bounds__(256)
render_kernel(const float4* __restrict__ params,
              const int* __restrict__ starts,
              const int* __restrict__ list,
              float* __restrict__ out) {
    int tile = blockIdx.x;
    int tx = tile & (TX - 1), ty = tile / TX;
    int lx = threadIdx.x & (TILE - 1), ly = threadIdx.x / TILE;
    int px = tx * TILE + lx, py = ty * TILE + ly;
    float fpx = (float)px, fpy = (float)py;

    __shared__ float4 sp[CHUNK * 3];

    float fr = 0.f, fg = 0.f, fb = 0.f, fw = 0.f;
    int beg = starts[tile], end = starts[tile + 1];

    for (int c = beg; c < end; c += CHUNK) {
        int n = min(CHUNK, end - c);
        __syncthreads();
        for (int i = threadIdx.x; i < n * 3; i += 256) {
            int gi = list[c + i / 3];
            sp[i] = params[3 * gi + (i % 3)];
        }
        __syncthreads();
        for (int j = 0; j < n; ++j) {
            float4 p0 = sp[3 * j + 0];
            float4 p1 = sp[3 * j + 1];
            float4 p2 = sp[3 * j + 2];
            int bx = (int)p2.z, by = (int)p2.w;
            unsigned ox = (unsigned)(px - bx + PP / 2);
            unsigned oy = (unsigned)(py - by + PP / 2);
            if (ox < PP && oy < PP) {
                float dx = fpx - p0.x;
                float dy = fpy - p0.y;
                float vx = p0.z * dx + p0.w * dy;
                float vy = p1.x * dx + p1.y * dy;
                float w = p1.z * __expf(-0.5f * (vx * vx + vy * vy));
                fr += w * p1.w;
                fg += w * p2.x;
                fb += w * p2.y;
                fw += w;
            }
        }
    }

    float inv = 1.0f / (fw + 1e-6f);
    int idx = py * WW + px;
    out[3 * idx + 0] = fr * inv;
    out[3 * idx + 1] = fg * inv;
    out[3 * idx + 2] = fb * inv;
}

extern "C" void kernel_launch(void* const* d_in, const int* in_sizes, int n_in,
                              void* d_out, int out_size, void* d_ws, size_t ws_size,
                              hipStream_t stream) {
    const float* xyz  = (const float*)d_in[0];
    const float* feat = (const float*)d_in[1];
    const float* opac = (const float*)d_in[2];
    const float* scal = (const float*)d_in[3];
    const float* rot  = (const float*)d_in[4];
    float* out = (float*)d_out;

    char* ws = (char*)d_ws;
    size_t off = 0;
    float4* params = (float4*)(ws + off); off += (size_t)NG * 3 * sizeof(float4);
    int* counts = (int*)(ws + off);       off += (size_t)NTILES * sizeof(int);
    int* starts = (int*)(ws + off);       off += (size_t)(NTILES + 1) * sizeof(int);
    off = (off + 255) & ~(size_t)255;
    int* cursor = (int*)(ws + off);       off += (size_t)NTILES * sizeof(int);
    int* list   = (int*)(ws + off);

    hipMemsetAsync(counts, 0, (size_t)NTILES * sizeof(int), stream);

    prep_kernel<<<NG / 256, 256, 0, stream>>>(xyz, feat, opac, scal, rot, params);
    count_kernel<<<NG / 256, 256, 0, stream>>>(params, counts);
    scan_kernel<<<1, 256, 0, stream>>>(counts, starts, cursor);
    fill_kernel<<<NG / 256, 256, 0, stream>>>(params, cursor, list);
    render_kernel<<<NTILES, 256, 0, stream>>>(params, starts, list, out);
}